// Round 3
// baseline (1602.324 us; speedup 1.0000x reference)
//
#include <hip/hip_runtime.h>
#include <math.h>

#define NN 768
#define CS 384
#define CZ 128
#define CH 16
#define HH 12
#define PQ 4
#define PV 8
#define OUTIN 2112

#define SC_QK 0.14433756729740643f   // sqrt(1/(3*16))
#define SC_B  0.57735026918962576f   // sqrt(1/3)
#define SC_HW 0.13608276348795434f   // sqrt(2/(27*4))

// ---------------- Kernel A: input projections (s @ W.T + b) ----------------
__global__ __launch_bounds__(256) void kproj(
    const float* __restrict__ s,
    const float* __restrict__ Wq,  const float* __restrict__ bq,
    const float* __restrict__ Wkv, const float* __restrict__ bkv,
    const float* __restrict__ Wqp, const float* __restrict__ bqp,
    const float* __restrict__ Wkvp,const float* __restrict__ bkvp,
    float* __restrict__ q, float* __restrict__ kT, float* __restrict__ vall,
    float* __restrict__ qpr, float* __restrict__ kvpr)
{
    __shared__ float s_lds[8*384];
    int n0 = blockIdx.x * 8;
    int t = threadIdx.x;
    for (int idx = t; idx < 8*384; idx += 256)
        s_lds[idx] = s[(n0 + idx/384)*384 + (idx%384)];
    __syncthreads();

    int o = blockIdx.y * 128 + (t & 127);
    int ng = t >> 7;
    const float* wrow; float bias;
    if (o < 192)      { wrow = Wq   + o*384;       bias = bq[o]; }
    else if (o < 576) { wrow = Wkv  + (o-192)*384; bias = bkv[o-192]; }
    else if (o < 720) { wrow = Wqp  + (o-576)*384; bias = bqp[o-576]; }
    else              { wrow = Wkvp + (o-720)*384; bias = bkvp[o-720]; }

    float acc[4] = {bias, bias, bias, bias};
    const float4* wr4 = reinterpret_cast<const float4*>(wrow);
    for (int c4 = 0; c4 < 96; ++c4) {
        float4 w = wr4[c4];
        #pragma unroll
        for (int nn = 0; nn < 4; ++nn) {
            const float* sr = &s_lds[(ng*4+nn)*384 + c4*4];
            acc[nn] = fmaf(w.x, sr[0], acc[nn]);
            acc[nn] = fmaf(w.y, sr[1], acc[nn]);
            acc[nn] = fmaf(w.z, sr[2], acc[nn]);
            acc[nn] = fmaf(w.w, sr[3], acc[nn]);
        }
    }
    #pragma unroll
    for (int nn = 0; nn < 4; ++nn) {
        int n = n0 + ng*4 + nn;
        float v = acc[nn];
        if (o < 192)      q[n*192 + o] = v;
        else if (o < 576) {
            int oo = o - 192, h = oo >> 5, cc = oo & 31;
            if (cc < 16) kT[(h*NN + n)*16 + cc] = v;
            else         vall[(size_t)n*480 + h*40 + (cc-16)] = v;
        }
        else if (o < 720) qpr[n*144 + (o-576)] = v;
        else              kvpr[n*432 + (o-720)] = v;
    }
}

// ---------------- Kernel B: apply frames (rot, trans) to points ----------------
__global__ __launch_bounds__(192) void krot(
    const float* __restrict__ rot, const float* __restrict__ trans,
    const float* __restrict__ qpr, const float* __restrict__ kvpr,
    float* __restrict__ qp, float* __restrict__ kpT, float* __restrict__ vall)
{
    int n = blockIdx.x;
    __shared__ float R[9], T[3];
    int t = threadIdx.x;
    if (t < 9) R[t] = rot[n*9 + t];
    if (t < 3) T[t] = trans[n*3 + t];
    __syncthreads();

    const float* src = (t < 48) ? (qpr + n*144 + t*3) : (kvpr + n*432 + (t-48)*3);
    float x = src[0], y = src[1], z = src[2];
    float wx = R[0]*x + R[1]*y + R[2]*z + T[0];
    float wy = R[3]*x + R[4]*y + R[5]*z + T[1];
    float wz = R[6]*x + R[7]*y + R[8]*z + T[2];
    if (t < 48) {
        float* d = qp + n*144 + t*3;
        d[0]=wx; d[1]=wy; d[2]=wz;
    } else {
        int pi = t - 48, h = pi/12, pp = pi%12;
        float* d = (pp < 4) ? (kpT + (h*NN+n)*12 + pp*3)
                            : (vall + (size_t)n*480 + h*40 + 16 + (pp-4)*3);
        d[0]=wx; d[1]=wy; d[2]=wz;
    }
}

// ---------------- Kernel C: fused attention, LDS-staged z ----------------
__global__ __launch_bounds__(256, 3) void kattn(
    const float* __restrict__ z, const float* __restrict__ mask,
    const float* __restrict__ Wb, const float* __restrict__ bb,
    const float* __restrict__ head_w,
    const float* __restrict__ rot, const float* __restrict__ trans,
    const float* __restrict__ q, const float* __restrict__ kT,
    const float* __restrict__ kpT, const float* __restrict__ vall,
    const float* __restrict__ qp, float* __restrict__ cat)
{
    __shared__ float4 z_lds4[64][32];          // 32 KB, swizzled: [j][c4 ^ (j&7)]
    __shared__ float4 wb4[12*32];              // 6 KB
    __shared__ float  p_lds[12][68];
    __shared__ float  q_lds[192], qp_lds[144];
    __shared__ float  corr_lds[12], lrun_lds[12], hw_lds[12], bb_lds[12];
    __shared__ float  R[9], T[3];
    __shared__ float  opt_lds[12][24];

    const int i = blockIdx.x;
    const int t = threadIdx.x;
    const int w = t >> 6, l = t & 63;
    const int h0 = w * 3;

    for (int idx = t; idx < 192; idx += 256) q_lds[idx]  = q[i*192 + idx];
    for (int idx = t; idx < 144; idx += 256) qp_lds[idx] = qp[i*144 + idx];
    for (int idx = t; idx < 384; idx += 256) wb4[idx] = reinterpret_cast<const float4*>(Wb)[idx];
    if (t < 12) { hw_lds[t] = log1pf(expf(head_w[t])) * SC_HW; bb_lds[t] = bb[t]; }
    if (t < 9) R[t] = rot[i*9 + t];
    if (t < 3) T[t] = trans[i*3 + t];

    const size_t zrow = (size_t)i * NN * CZ;

    // ---- stage tile 0 (swizzled source, linear LDS dest) ----
    #pragma unroll
    for (int k = 0; k < 8; ++k) {
        int s4 = (w*8 + k)*64 + l;
        int j  = s4 >> 5, sl = s4 & 31;
        const float* g = z + zrow + (size_t)j*CZ + (((sl ^ (j & 7)) << 2));
        __builtin_amdgcn_global_load_lds(
            (const __attribute__((address_space(1))) void*)g,
            (__attribute__((address_space(3))) void*)((char*)&z_lds4[0][0] + (size_t)s4*16),
            16, 0, 0);
    }

    float m_run[3] = {-1e30f, -1e30f, -1e30f};
    float l_run[3] = {0.f, 0.f, 0.f};
    float2 opz[3]  = {{0.f,0.f},{0.f,0.f},{0.f,0.f}};
    float2 ovv     = {0.f, 0.f};
    const int bh = t / 20, be = (t % 20) * 2;
    const float maski = mask[i];
    float hwv[3], bbv[3];

    __syncthreads();
    #pragma unroll
    for (int hi = 0; hi < 3; ++hi) { hwv[hi] = hw_lds[h0+hi]; bbv[hi] = bb_lds[h0+hi]; }

    for (int tile = 0; tile < 12; ++tile) {
        const int j0 = tile * 64;
        if (tile) __syncthreads();   // A: stage of this tile complete, p_lds free
        const int j = j0 + l;

        // ---- phase 1: logits for 3 heads at column j ----
        float qk[3], d2[3];
        #pragma unroll
        for (int hi = 0; hi < 3; ++hi) {
            const float4* kr = reinterpret_cast<const float4*>(kT) + ((size_t)((h0+hi)*NN + j) << 2);
            float4 k0 = kr[0], k1 = kr[1], k2 = kr[2], k3 = kr[3];
            const float4* qr = reinterpret_cast<const float4*>(q_lds + (h0+hi)*16);
            float4 q0 = qr[0], q1 = qr[1], q2 = qr[2], q3 = qr[3];
            float acc = k0.x*q0.x + k0.y*q0.y + k0.z*q0.z + k0.w*q0.w;
            acc = fmaf(k1.x, q1.x, acc); acc = fmaf(k1.y, q1.y, acc);
            acc = fmaf(k1.z, q1.z, acc); acc = fmaf(k1.w, q1.w, acc);
            acc = fmaf(k2.x, q2.x, acc); acc = fmaf(k2.y, q2.y, acc);
            acc = fmaf(k2.z, q2.z, acc); acc = fmaf(k2.w, q2.w, acc);
            acc = fmaf(k3.x, q3.x, acc); acc = fmaf(k3.y, q3.y, acc);
            acc = fmaf(k3.z, q3.z, acc); acc = fmaf(k3.w, q3.w, acc);
            qk[hi] = acc;

            const float4* pr = reinterpret_cast<const float4*>(kpT) + (size_t)((h0+hi)*NN + j)*3;
            float4 a0 = pr[0], a1 = pr[1], a2 = pr[2];
            const float* qpv = qp_lds + (h0+hi)*12;
            float d, s2;
            d = qpv[0]  - a0.x; s2 = d*d;
            d = qpv[1]  - a0.y; s2 = fmaf(d,d,s2);
            d = qpv[2]  - a0.z; s2 = fmaf(d,d,s2);
            d = qpv[3]  - a0.w; s2 = fmaf(d,d,s2);
            d = qpv[4]  - a1.x; s2 = fmaf(d,d,s2);
            d = qpv[5]  - a1.y; s2 = fmaf(d,d,s2);
            d = qpv[6]  - a1.z; s2 = fmaf(d,d,s2);
            d = qpv[7]  - a1.w; s2 = fmaf(d,d,s2);
            d = qpv[8]  - a2.x; s2 = fmaf(d,d,s2);
            d = qpv[9]  - a2.y; s2 = fmaf(d,d,s2);
            d = qpv[10] - a2.z; s2 = fmaf(d,d,s2);
            d = qpv[11] - a2.w; s2 = fmaf(d,d,s2);
            d2[hi] = s2;
        }

        // bias: z row (from swizzled LDS) dot Wb rows (broadcast)
        float b0 = bbv[0], b1 = bbv[1], b2 = bbv[2];
        const int sw = l & 7;
        #pragma unroll 4
        for (int c4 = 0; c4 < 32; ++c4) {
            float4 zv = z_lds4[l][c4 ^ sw];
            float4 w0 = wb4[(h0+0)*32 + c4];
            float4 w1 = wb4[(h0+1)*32 + c4];
            float4 w2 = wb4[(h0+2)*32 + c4];
            b0 = fmaf(zv.x,w0.x,b0); b0 = fmaf(zv.y,w0.y,b0); b0 = fmaf(zv.z,w0.z,b0); b0 = fmaf(zv.w,w0.w,b0);
            b1 = fmaf(zv.x,w1.x,b1); b1 = fmaf(zv.y,w1.y,b1); b1 = fmaf(zv.z,w1.z,b1); b1 = fmaf(zv.w,w1.w,b1);
            b2 = fmaf(zv.x,w2.x,b2); b2 = fmaf(zv.y,w2.y,b2); b2 = fmaf(zv.z,w2.z,b2); b2 = fmaf(zv.w,w2.w,b2);
        }

        const float mterm = 1e9f * (maski * mask[j] - 1.0f);
        float lg[3];
        lg[0] = fmaf(qk[0], SC_QK, fmaf(b0, SC_B, -0.5f*hwv[0]*d2[0])) + mterm;
        lg[1] = fmaf(qk[1], SC_QK, fmaf(b1, SC_B, -0.5f*hwv[1]*d2[1])) + mterm;
        lg[2] = fmaf(qk[2], SC_QK, fmaf(b2, SC_B, -0.5f*hwv[2]*d2[2])) + mterm;

        // ---- online softmax ----
        float mx0 = lg[0], mx1 = lg[1], mx2 = lg[2];
        #pragma unroll
        for (int off = 32; off >= 1; off >>= 1) {
            mx0 = fmaxf(mx0, __shfl_xor(mx0, off, 64));
            mx1 = fmaxf(mx1, __shfl_xor(mx1, off, 64));
            mx2 = fmaxf(mx2, __shfl_xor(mx2, off, 64));
        }
        float mn0 = fmaxf(m_run[0], mx0), mn1 = fmaxf(m_run[1], mx1), mn2 = fmaxf(m_run[2], mx2);
        float cr0 = __expf(m_run[0]-mn0), cr1 = __expf(m_run[1]-mn1), cr2 = __expf(m_run[2]-mn2);
        float p0 = __expf(lg[0]-mn0), p1 = __expf(lg[1]-mn1), p2 = __expf(lg[2]-mn2);
        float s0 = p0, s1 = p1, s2s = p2;
        #pragma unroll
        for (int off = 32; off >= 1; off >>= 1) {
            s0  += __shfl_xor(s0, off, 64);
            s1  += __shfl_xor(s1, off, 64);
            s2s += __shfl_xor(s2s, off, 64);
        }
        l_run[0] = fmaf(l_run[0], cr0, s0);
        l_run[1] = fmaf(l_run[1], cr1, s1);
        l_run[2] = fmaf(l_run[2], cr2, s2s);
        m_run[0] = mn0; m_run[1] = mn1; m_run[2] = mn2;

        p_lds[h0+0][l] = p0;
        p_lds[h0+1][l] = p1;
        p_lds[h0+2][l] = p2;
        if (l == 0) { corr_lds[h0+0] = cr0; corr_lds[h0+1] = cr1; corr_lds[h0+2] = cr2; }

        opz[0].x *= cr0; opz[0].y *= cr0;
        opz[1].x *= cr1; opz[1].y *= cr1;
        opz[2].x *= cr2; opz[2].y *= cr2;

        __syncthreads();   // B: p_lds / corr_lds visible

        // ---- phase 2: o_pair accumulate. lane = float2-column; NO address-taken
        //      vector indexing (rule #20): extract via .x/.y/.z/.w only. ----
        const int c2h = l >> 1, c2lo = (l & 1) * 2;
        #define P2_STEP(JL, FA, FB, FC)                                               \
        {                                                                             \
            const int jl_ = (JL);                                                     \
            const float* zp = reinterpret_cast<const float*>(                         \
                &z_lds4[jl_][c2h ^ (jl_ & 7)]) + c2lo;                                \
            float zx = zp[0], zy = zp[1];                                             \
            opz[0].x = fmaf(FA, zx, opz[0].x); opz[0].y = fmaf(FA, zy, opz[0].y);     \
            opz[1].x = fmaf(FB, zx, opz[1].x); opz[1].y = fmaf(FB, zy, opz[1].y);     \
            opz[2].x = fmaf(FC, zx, opz[2].x); opz[2].y = fmaf(FC, zy, opz[2].y);     \
        }
        for (int j4 = 0; j4 < 16; ++j4) {
            float4 pA = *reinterpret_cast<const float4*>(&p_lds[h0+0][j4<<2]);
            float4 pB = *reinterpret_cast<const float4*>(&p_lds[h0+1][j4<<2]);
            float4 pC = *reinterpret_cast<const float4*>(&p_lds[h0+2][j4<<2]);
            P2_STEP((j4<<2)|0, pA.x, pB.x, pC.x);
            P2_STEP((j4<<2)|1, pA.y, pB.y, pC.y);
            P2_STEP((j4<<2)|2, pA.z, pB.z, pC.z);
            P2_STEP((j4<<2)|3, pA.w, pB.w, pC.w);
        }
        #undef P2_STEP

        __syncthreads();   // C: z_lds reads done -> safe to overwrite

        // ---- prefetch next z tile (async; drains at barrier A) ----
        if (tile + 1 < 12) {
            const int jn0 = (tile + 1) * 64;
            #pragma unroll
            for (int k = 0; k < 8; ++k) {
                int s4 = (w*8 + k)*64 + l;
                int jj = s4 >> 5, sl = s4 & 31;
                const float* g = z + zrow + (size_t)(jn0 + jj)*CZ + (((sl ^ (jj & 7)) << 2));
                __builtin_amdgcn_global_load_lds(
                    (const __attribute__((address_space(1))) void*)g,
                    (__attribute__((address_space(3))) void*)((char*)&z_lds4[0][0] + (size_t)s4*16),
                    16, 0, 0);
            }
        }

        // ---- phase 2b: o (v) + o_pt (v_pts) accumulate, overlaps prefetch ----
        if (t < 240) {
            float cb = corr_lds[bh];
            ovv.x *= cb; ovv.y *= cb;
            const float* vp = vall + (size_t)j0*480 + bh*40 + be;
            #pragma unroll 4
            for (int jl = 0; jl < 64; ++jl) {
                float2 vv = *reinterpret_cast<const float2*>(vp + (size_t)jl*480);
                float pj = p_lds[bh][jl];
                ovv.x = fmaf(pj, vv.x, ovv.x);
                ovv.y = fmaf(pj, vv.y, ovv.y);
            }
        }
    }

    // ---- finalize ----
    float* crow = cat + (size_t)i * OUTIN;
    if (l == 0) {
        lrun_lds[h0+0] = l_run[0]; lrun_lds[h0+1] = l_run[1]; lrun_lds[h0+2] = l_run[2];
    }
    #pragma unroll
    for (int hi = 0; hi < 3; ++hi) {
        float inv = 1.0f / l_run[hi];
        float2 o2 = { opz[hi].x * inv, opz[hi].y * inv };
        *reinterpret_cast<float2*>(&crow[576 + (h0+hi)*128 + 2*l]) = o2;
    }
    __syncthreads();
    if (t < 240) {
        float invb = 1.0f / lrun_lds[bh];
        float a0 = ovv.x * invb, a1 = ovv.y * invb;
        if (be < 16) { crow[bh*16 + be] = a0; crow[bh*16 + be + 1] = a1; }
        else         { opt_lds[bh][be-16] = a0; opt_lds[bh][be-15] = a1; }
    }
    __syncthreads();
    if (t < 96) {
        int h = t >> 3, p = t & 7;
        float wx = opt_lds[h][p*3+0] - T[0];
        float wy = opt_lds[h][p*3+1] - T[1];
        float wz = opt_lds[h][p*3+2] - T[2];
        crow[192 + 0*96 + h*8 + p] = R[0]*wx + R[3]*wy + R[6]*wz;
        crow[192 + 1*96 + h*8 + p] = R[1]*wx + R[4]*wy + R[7]*wz;
        crow[192 + 2*96 + h*8 + p] = R[2]*wx + R[5]*wy + R[8]*wz;
        crow[480 + h*8 + p] = sqrtf(fmaf(wx,wx,fmaf(wy,wy,wz*wz)) + 1e-8f);
    }
}

// ---------------- Kernel D: output projection (cat @ Wout.T + bout) ----------------
__global__ __launch_bounds__(256) void kout(
    const float* __restrict__ cat, const float* __restrict__ Wout,
    const float* __restrict__ bout, float* __restrict__ out)
{
    __shared__ float c_lds[8*528];
    int n0 = blockIdx.x * 8;
    int t = threadIdx.x;
    int o = blockIdx.y * 128 + (t & 127);
    int ng = t >> 7;
    float b = bout[o];
    float acc[4] = {b, b, b, b};
    for (int ch = 0; ch < 4; ++ch) {
        __syncthreads();
        for (int idx = t; idx < 8*528; idx += 256)
            c_lds[idx] = cat[(size_t)(n0 + idx/528)*OUTIN + ch*528 + (idx%528)];
        __syncthreads();
        const float4* wr = reinterpret_cast<const float4*>(Wout + (size_t)o*OUTIN + ch*528);
        for (int c4 = 0; c4 < 132; ++c4) {
            float4 wv = wr[c4];
            #pragma unroll
            for (int nn = 0; nn < 4; ++nn) {
                const float* cr = &c_lds[(ng*4+nn)*528 + c4*4];
                acc[nn] = fmaf(wv.x, cr[0], acc[nn]);
                acc[nn] = fmaf(wv.y, cr[1], acc[nn]);
                acc[nn] = fmaf(wv.z, cr[2], acc[nn]);
                acc[nn] = fmaf(wv.w, cr[3], acc[nn]);
            }
        }
    }
    #pragma unroll
    for (int nn = 0; nn < 4; ++nn)
        out[(size_t)(n0 + ng*4 + nn)*384 + o] = acc[nn];
}

extern "C" void kernel_launch(void* const* d_in, const int* in_sizes, int n_in,
                              void* d_out, int out_size, void* d_ws, size_t ws_size,
                              hipStream_t stream) {
    const float* s      = (const float*)d_in[0];
    const float* z      = (const float*)d_in[1];
    const float* rot    = (const float*)d_in[2];
    const float* trans  = (const float*)d_in[3];
    const float* mask   = (const float*)d_in[4];
    const float* Wq     = (const float*)d_in[5];
    const float* bq     = (const float*)d_in[6];
    const float* Wkv    = (const float*)d_in[7];
    const float* bkv    = (const float*)d_in[8];
    const float* Wqp    = (const float*)d_in[9];
    const float* bqp    = (const float*)d_in[10];
    const float* Wkvp   = (const float*)d_in[11];
    const float* bkvp   = (const float*)d_in[12];
    const float* Wb     = (const float*)d_in[13];
    const float* bb     = (const float*)d_in[14];
    const float* head_w = (const float*)d_in[15];
    const float* Wout   = (const float*)d_in[16];
    const float* bout   = (const float*)d_in[17];
    float* out = (float*)d_out;
    float* ws  = (float*)d_ws;

    float* q    = ws;             // 768*192          = 147456
    float* kT   = ws + 147456;    // 12*768*16        = 147456
    float* kpT  = ws + 294912;    // 12*768*12        = 110592
    float* vall = ws + 405504;    // 768*480          = 368640
    float* qp   = ws + 774144;    // 768*144          = 110592
    float* qpr  = ws + 884736;    // 768*144          = 110592
    float* kvpr = ws + 995328;    // 768*432          = 331776
    float* cat  = ws + 1327104;   // 768*2112         = 1622016

    kproj<<<dim3(96, 9), 256, 0, stream>>>(s, Wq, bq, Wkv, bkv, Wqp, bqp, Wkvp, bkvp,
                                           q, kT, vall, qpr, kvpr);
    krot<<<dim3(768), 192, 0, stream>>>(rot, trans, qpr, kvpr, qp, kpT, vall);
    kattn<<<dim3(768), 256, 0, stream>>>(z, mask, Wb, bb, head_w, rot, trans,
                                         q, kT, kpT, vall, qp, cat);
    kout<<<dim3(96, 3), 256, 0, stream>>>(cat, Wout, bout, out);
}

// Round 4
// 552.666 us; speedup vs baseline: 2.8993x; 2.8993x over previous
//
#include <hip/hip_runtime.h>
#include <math.h>

#define NN 768
#define CS 384
#define CZ 128
#define CH 16
#define HH 12
#define PQ 4
#define PV 8
#define OUTIN 2112

#define SC_QK 0.14433756729740643f   // sqrt(1/(3*16))
#define SC_B  0.57735026918962576f   // sqrt(1/3)
#define SC_HW 0.13608276348795434f   // sqrt(2/(27*4))

// ---------------- Kernel A: input projections (s @ W.T + b) ----------------
__global__ __launch_bounds__(256) void kproj(
    const float* __restrict__ s,
    const float* __restrict__ Wq,  const float* __restrict__ bq,
    const float* __restrict__ Wkv, const float* __restrict__ bkv,
    const float* __restrict__ Wqp, const float* __restrict__ bqp,
    const float* __restrict__ Wkvp,const float* __restrict__ bkvp,
    float* __restrict__ q, float* __restrict__ kT, float* __restrict__ vall,
    float* __restrict__ qpr, float* __restrict__ kvpr)
{
    __shared__ float s_lds[8*384];
    int n0 = blockIdx.x * 8;
    int t = threadIdx.x;
    for (int idx = t; idx < 8*384; idx += 256)
        s_lds[idx] = s[(n0 + idx/384)*384 + (idx%384)];
    __syncthreads();

    int o = blockIdx.y * 128 + (t & 127);
    int ng = t >> 7;
    const float* wrow; float bias;
    if (o < 192)      { wrow = Wq   + o*384;       bias = bq[o]; }
    else if (o < 576) { wrow = Wkv  + (o-192)*384; bias = bkv[o-192]; }
    else if (o < 720) { wrow = Wqp  + (o-576)*384; bias = bqp[o-576]; }
    else              { wrow = Wkvp + (o-720)*384; bias = bkvp[o-720]; }

    float acc[4] = {bias, bias, bias, bias};
    const float4* wr4 = reinterpret_cast<const float4*>(wrow);
    for (int c4 = 0; c4 < 96; ++c4) {
        float4 w = wr4[c4];
        #pragma unroll
        for (int nn = 0; nn < 4; ++nn) {
            const float* sr = &s_lds[(ng*4+nn)*384 + c4*4];
            acc[nn] = fmaf(w.x, sr[0], acc[nn]);
            acc[nn] = fmaf(w.y, sr[1], acc[nn]);
            acc[nn] = fmaf(w.z, sr[2], acc[nn]);
            acc[nn] = fmaf(w.w, sr[3], acc[nn]);
        }
    }
    #pragma unroll
    for (int nn = 0; nn < 4; ++nn) {
        int n = n0 + ng*4 + nn;
        float v = acc[nn];
        if (o < 192)      q[n*192 + o] = v;
        else if (o < 576) {
            int oo = o - 192, h = oo >> 5, cc = oo & 31;
            if (cc < 16) kT[(h*NN + n)*16 + cc] = v;
            else         vall[(size_t)n*480 + h*40 + (cc-16)] = v;
        }
        else if (o < 720) qpr[n*144 + (o-576)] = v;
        else              kvpr[n*432 + (o-720)] = v;
    }
}

// ---------------- Kernel B: apply frames (rot, trans) to points ----------------
__global__ __launch_bounds__(192) void krot(
    const float* __restrict__ rot, const float* __restrict__ trans,
    const float* __restrict__ qpr, const float* __restrict__ kvpr,
    float* __restrict__ qp, float* __restrict__ kpT, float* __restrict__ vall)
{
    int n = blockIdx.x;
    __shared__ float R[9], T[3];
    int t = threadIdx.x;
    if (t < 9) R[t] = rot[n*9 + t];
    if (t < 3) T[t] = trans[n*3 + t];
    __syncthreads();

    const float* src = (t < 48) ? (qpr + n*144 + t*3) : (kvpr + n*432 + (t-48)*3);
    float x = src[0], y = src[1], z = src[2];
    float wx = R[0]*x + R[1]*y + R[2]*z + T[0];
    float wy = R[3]*x + R[4]*y + R[5]*z + T[1];
    float wz = R[6]*x + R[7]*y + R[8]*z + T[2];
    if (t < 48) {
        float* d = qp + n*144 + t*3;
        d[0]=wx; d[1]=wy; d[2]=wz;
    } else {
        int pi = t - 48, h = pi/12, pp = pi%12;
        float* d = (pp < 4) ? (kpT + (h*NN+n)*12 + pp*3)
                            : (vall + (size_t)n*480 + h*40 + 16 + (pp-4)*3);
        d[0]=wx; d[1]=wy; d[2]=wz;
    }
}

// ---------------- Kernel C1: z-independent logit part ----------------
// lqd[h,i,j] = SC_QK*qk - 0.5*hw*d2 + bb[h] + 1e9*(mask_i*mask_j - 1)
// grid (6 j-tiles of 128, 24 i-tiles of 32, 12 h), block 256.
__global__ __launch_bounds__(256) void kqk(
    const float* __restrict__ kT, const float* __restrict__ kpT,
    const float* __restrict__ q, const float* __restrict__ qp,
    const float* __restrict__ mask, const float* __restrict__ head_w,
    const float* __restrict__ bb, float* __restrict__ lqd)
{
    const int h = blockIdx.z;
    const int j0 = blockIdx.x * 128;
    const int i0 = blockIdx.y * 32;
    __shared__ float kt_l[16][132], kp_l[12][132];
    __shared__ float q_l[32][16], qp_l[32][12];
    __shared__ float mi_l[32], mj_l[128];
    const int t = threadIdx.x;
    for (int idx = t; idx < 2048; idx += 256) {
        int j = idx >> 4, c = idx & 15;
        kt_l[c][j] = kT[(size_t)(h*NN + j0 + j)*16 + c];
    }
    for (int idx = t; idx < 1536; idx += 256) {
        int j = idx / 12, e = idx - j*12;
        kp_l[e][j] = kpT[(size_t)(h*NN + j0 + j)*12 + e];
    }
    for (int idx = t; idx < 512; idx += 256) {
        int ii = idx >> 4, c = idx & 15;
        q_l[ii][c] = q[(i0+ii)*192 + h*16 + c];
    }
    for (int idx = t; idx < 384; idx += 256) {
        int ii = idx / 12, e = idx - ii*12;
        qp_l[ii][e] = qp[(i0+ii)*144 + h*12 + e];
    }
    if (t < 32)  mi_l[t] = mask[i0 + t];
    if (t < 128) mj_l[t] = mask[j0 + t];
    const float hwh = log1pf(expf(head_w[h])) * SC_HW;
    const float bbh = bb[h];
    __syncthreads();

    const int jl = t & 127, ig = t >> 7;
    const float mj = mj_l[jl];
    #pragma unroll 4
    for (int ii = 0; ii < 16; ++ii) {
        const int il = ig*16 + ii;
        float qk = 0.f;
        #pragma unroll
        for (int c = 0; c < 16; ++c) qk = fmaf(kt_l[c][jl], q_l[il][c], qk);
        float d2 = 0.f;
        #pragma unroll
        for (int e = 0; e < 12; ++e) { float d = qp_l[il][e] - kp_l[e][jl]; d2 = fmaf(d, d, d2); }
        float mt = 1e9f * (mi_l[il]*mj - 1.0f);
        float lg = fmaf(qk, SC_QK, fmaf(-0.5f*hwh, d2, bbh)) + mt;
        lqd[((size_t)h*NN + i0 + il)*NN + j0 + jl] = lg;
    }
}

// ---------------- Kernel C2: bias (z·Wb) + full-row softmax ----------------
// One block per query row i. Writes UNNORMALIZED exp(lg - m) to a, row sums to lsum.
// z tile reg-staged into LDS with XOR swizzle; no global_load_lds anywhere.
__global__ __launch_bounds__(256, 2) void kbias(
    const float* __restrict__ z, const float* __restrict__ Wb,
    const float* __restrict__ lqd, float* __restrict__ a, float* __restrict__ lsum)
{
    __shared__ float4 zt4[64][32];         // 32 KB, read as [l][c4 ^ (l&7)]
    __shared__ float  arow[12][776];       // 37.2 KB raw logits
    __shared__ float4 wb4l[12*32];         // 6 KB

    const int i = blockIdx.x, t = threadIdx.x;
    const int w = t >> 6, l = t & 63, h0 = w*3;
    for (int idx = t; idx < 384; idx += 256) wb4l[idx] = ((const float4*)Wb)[idx];

    const float4* zg = (const float4*)(z + (size_t)i*NN*CZ);  // 768*32 float4
    float4 stg[8];
    #pragma unroll
    for (int k = 0; k < 8; ++k) stg[k] = zg[k*256 + t];
    #pragma unroll
    for (int k = 0; k < 8; ++k) {
        int slot = k*256 + t, j = slot >> 5, c4 = slot & 31;
        zt4[j][c4 ^ (j & 7)] = stg[k];
    }

    float mrun0 = -1e30f, mrun1 = -1e30f, mrun2 = -1e30f;
    const int swl = l & 7;

    for (int tile = 0; tile < 12; ++tile) {
        __syncthreads();   // stage (and wb4l on first iter) visible
        if (tile + 1 < 12) {   // T14: issue next tile's loads before compute
            #pragma unroll
            for (int k = 0; k < 8; ++k) stg[k] = zg[(tile+1)*2048 + k*256 + t];
        }
        const int j = tile*64 + l;
        float lq0 = lqd[((size_t)(h0+0)*NN + i)*NN + j];
        float lq1 = lqd[((size_t)(h0+1)*NN + i)*NN + j];
        float lq2 = lqd[((size_t)(h0+2)*NN + i)*NN + j];
        float b0 = 0.f, b1 = 0.f, b2 = 0.f;
        #pragma unroll 8
        for (int c4 = 0; c4 < 32; ++c4) {
            float4 zv = zt4[l][c4 ^ swl];
            float4 w0 = wb4l[(h0+0)*32 + c4];
            float4 w1 = wb4l[(h0+1)*32 + c4];
            float4 w2 = wb4l[(h0+2)*32 + c4];
            b0 = fmaf(zv.x,w0.x,b0); b0 = fmaf(zv.y,w0.y,b0); b0 = fmaf(zv.z,w0.z,b0); b0 = fmaf(zv.w,w0.w,b0);
            b1 = fmaf(zv.x,w1.x,b1); b1 = fmaf(zv.y,w1.y,b1); b1 = fmaf(zv.z,w1.z,b1); b1 = fmaf(zv.w,w1.w,b1);
            b2 = fmaf(zv.x,w2.x,b2); b2 = fmaf(zv.y,w2.y,b2); b2 = fmaf(zv.z,w2.z,b2); b2 = fmaf(zv.w,w2.w,b2);
        }
        float g0 = fmaf(b0, SC_B, lq0);
        float g1 = fmaf(b1, SC_B, lq1);
        float g2 = fmaf(b2, SC_B, lq2);
        arow[h0+0][j] = g0; arow[h0+1][j] = g1; arow[h0+2][j] = g2;
        mrun0 = fmaxf(mrun0, g0); mrun1 = fmaxf(mrun1, g1); mrun2 = fmaxf(mrun2, g2);
        __syncthreads();   // zt4 reads done
        if (tile + 1 < 12) {
            #pragma unroll
            for (int k = 0; k < 8; ++k) {
                int slot = k*256 + t, jj = slot >> 5, c4 = slot & 31;
                zt4[jj][c4 ^ (jj & 7)] = stg[k];
            }
        }
    }

    #pragma unroll
    for (int off = 32; off >= 1; off >>= 1) {
        mrun0 = fmaxf(mrun0, __shfl_xor(mrun0, off, 64));
        mrun1 = fmaxf(mrun1, __shfl_xor(mrun1, off, 64));
        mrun2 = fmaxf(mrun2, __shfl_xor(mrun2, off, 64));
    }

    #define A2_HEAD(HOFF, MV)                                                  \
    {                                                                          \
        const int hh = h0 + (HOFF);                                            \
        float sum = 0.f;                                                       \
        float* ag = a + ((size_t)hh*NN + i)*NN;                                \
        _Pragma("unroll")                                                      \
        for (int k = 0; k < 12; ++k) {                                         \
            int jj = k*64 + l;                                                 \
            float p = __expf(arow[hh][jj] - (MV));                             \
            sum += p; ag[jj] = p;                                              \
        }                                                                      \
        _Pragma("unroll")                                                      \
        for (int off = 32; off >= 1; off >>= 1) sum += __shfl_xor(sum, off, 64);\
        if (l == 0) lsum[hh*NN + i] = sum;                                     \
    }
    A2_HEAD(0, mrun0)
    A2_HEAD(1, mrun1)
    A2_HEAD(2, mrun2)
    #undef A2_HEAD
}

// ---------------- Kernel C3: o_pair = a_norm @ z ----------------
// One block per row i; a-row normalized into LDS; z streamed coalesced.
__global__ __launch_bounds__(256, 4) void kopair(
    const float* __restrict__ z, const float* __restrict__ a,
    const float* __restrict__ lsum, float* __restrict__ cat)
{
    __shared__ float an_l[12][776];
    const int i = blockIdx.x, t = threadIdx.x;
    #pragma unroll
    for (int h = 0; h < 12; ++h) {
        const float inv = 1.0f / lsum[h*NN + i];
        const float* ag = a + ((size_t)h*NN + i)*NN;
        for (int j = t; j < NN; j += 256) an_l[h][j] = ag[j] * inv;
    }
    __syncthreads();

    const int c2 = t & 63, hg = t >> 6, h0 = hg*3;
    const float2* zp = (const float2*)(z + (size_t)i*NN*CZ) + c2;
    float a0x=0.f,a0y=0.f,a1x=0.f,a1y=0.f,a2x=0.f,a2y=0.f;
    #pragma unroll 8
    for (int j = 0; j < NN; ++j) {
        float2 zv = zp[(size_t)j*64];
        float p0 = an_l[h0+0][j], p1 = an_l[h0+1][j], p2 = an_l[h0+2][j];
        a0x = fmaf(p0, zv.x, a0x); a0y = fmaf(p0, zv.y, a0y);
        a1x = fmaf(p1, zv.x, a1x); a1y = fmaf(p1, zv.y, a1y);
        a2x = fmaf(p2, zv.x, a2x); a2y = fmaf(p2, zv.y, a2y);
    }
    float* crow = cat + (size_t)i*OUTIN + 576;
    float2 o0; o0.x = a0x; o0.y = a0y;
    float2 o1; o1.x = a1x; o1.y = a1y;
    float2 o2; o2.x = a2x; o2.y = a2y;
    *(float2*)(crow + (h0+0)*128 + 2*c2) = o0;
    *(float2*)(crow + (h0+1)*128 + 2*c2) = o1;
    *(float2*)(crow + (h0+2)*128 + 2*c2) = o2;
}

// ---------------- Kernel C4: o / o_pt = a_norm @ vall, + rotate/norm ----------------
__global__ __launch_bounds__(256, 4) void kov(
    const float* __restrict__ vall, const float* __restrict__ a,
    const float* __restrict__ lsum, const float* __restrict__ rot,
    const float* __restrict__ trans, float* __restrict__ cat)
{
    __shared__ float an_l[12][776];
    __shared__ float optl[12][24];
    __shared__ float R[9], T[3];
    const int i = blockIdx.x, t = threadIdx.x;
    if (t < 9) R[t] = rot[i*9 + t];
    if (t < 3) T[t] = trans[i*3 + t];
    #pragma unroll
    for (int h = 0; h < 12; ++h) {
        const float inv = 1.0f / lsum[h*NN + i];
        const float* ag = a + ((size_t)h*NN + i)*NN;
        for (int j = t; j < NN; j += 256) an_l[h][j] = ag[j] * inv;
    }
    __syncthreads();

    float* crow = cat + (size_t)i*OUTIN;
    if (t < 240) {
        const int h = t / 20, e = (t % 20)*2;
        const float2* vp = (const float2*)vall + t;
        float ax = 0.f, ay = 0.f;
        #pragma unroll 8
        for (int j = 0; j < NN; ++j) {
            float2 vv = vp[(size_t)j*240];
            float p = an_l[h][j];
            ax = fmaf(p, vv.x, ax); ay = fmaf(p, vv.y, ay);
        }
        if (e < 16) { crow[h*16 + e] = ax; crow[h*16 + e + 1] = ay; }
        else        { optl[h][e-16] = ax; optl[h][e-15] = ay; }
    }
    __syncthreads();
    if (t < 96) {
        int h = t >> 3, p = t & 7;
        float wx = optl[h][p*3+0] - T[0];
        float wy = optl[h][p*3+1] - T[1];
        float wz = optl[h][p*3+2] - T[2];
        crow[192 + 0*96 + h*8 + p] = R[0]*wx + R[3]*wy + R[6]*wz;
        crow[192 + 1*96 + h*8 + p] = R[1]*wx + R[4]*wy + R[7]*wz;
        crow[192 + 2*96 + h*8 + p] = R[2]*wx + R[5]*wy + R[8]*wz;
        crow[480 + h*8 + p] = sqrtf(fmaf(wx,wx,fmaf(wy,wy,wz*wz)) + 1e-8f);
    }
}

// ---------------- Kernel D: output projection (cat @ Wout.T + bout) ----------------
__global__ __launch_bounds__(256) void kout(
    const float* __restrict__ cat, const float* __restrict__ Wout,
    const float* __restrict__ bout, float* __restrict__ out)
{
    __shared__ float c_lds[8*528];
    int n0 = blockIdx.x * 8;
    int t = threadIdx.x;
    int o = blockIdx.y * 128 + (t & 127);
    int ng = t >> 7;
    float b = bout[o];
    float acc[4] = {b, b, b, b};
    for (int ch = 0; ch < 4; ++ch) {
        __syncthreads();
        for (int idx = t; idx < 8*528; idx += 256)
            c_lds[idx] = cat[(size_t)(n0 + idx/528)*OUTIN + ch*528 + (idx%528)];
        __syncthreads();
        const float4* wr = reinterpret_cast<const float4*>(Wout + (size_t)o*OUTIN + ch*528);
        for (int c4 = 0; c4 < 132; ++c4) {
            float4 wv = wr[c4];
            #pragma unroll
            for (int nn = 0; nn < 4; ++nn) {
                const float* cr = &c_lds[(ng*4+nn)*528 + c4*4];
                acc[nn] = fmaf(wv.x, cr[0], acc[nn]);
                acc[nn] = fmaf(wv.y, cr[1], acc[nn]);
                acc[nn] = fmaf(wv.z, cr[2], acc[nn]);
                acc[nn] = fmaf(wv.w, cr[3], acc[nn]);
            }
        }
    }
    #pragma unroll
    for (int nn = 0; nn < 4; ++nn)
        out[(size_t)(n0 + ng*4 + nn)*384 + o] = acc[nn];
}

extern "C" void kernel_launch(void* const* d_in, const int* in_sizes, int n_in,
                              void* d_out, int out_size, void* d_ws, size_t ws_size,
                              hipStream_t stream) {
    const float* s      = (const float*)d_in[0];
    const float* z      = (const float*)d_in[1];
    const float* rot    = (const float*)d_in[2];
    const float* trans  = (const float*)d_in[3];
    const float* mask   = (const float*)d_in[4];
    const float* Wq     = (const float*)d_in[5];
    const float* bq     = (const float*)d_in[6];
    const float* Wkv    = (const float*)d_in[7];
    const float* bkv    = (const float*)d_in[8];
    const float* Wqp    = (const float*)d_in[9];
    const float* bqp    = (const float*)d_in[10];
    const float* Wkvp   = (const float*)d_in[11];
    const float* bkvp   = (const float*)d_in[12];
    const float* Wb     = (const float*)d_in[13];
    const float* bb     = (const float*)d_in[14];
    const float* head_w = (const float*)d_in[15];
    const float* Wout   = (const float*)d_in[16];
    const float* bout   = (const float*)d_in[17];
    float* out = (float*)d_out;
    float* ws  = (float*)d_ws;

    float* q    = ws;              // 147456
    float* kT   = ws + 147456;     // 147456
    float* kpT  = ws + 294912;     // 110592
    float* vall = ws + 405504;     // 368640
    float* qp   = ws + 774144;     // 110592
    float* qpr  = ws + 884736;     // 110592
    float* kvpr = ws + 995328;     // 331776
    float* lsum = ws + 1327104;    // 9216
    float* cat  = ws + 1336320;    // 1622016
    float* lqd  = ws + 2958336;    // 12*768*768 = 7077888
    float* av   = ws + 10036224;   // 7077888  (ends at 17114112 floats = 68.5 MB)

    kproj<<<dim3(96, 9), 256, 0, stream>>>(s, Wq, bq, Wkv, bkv, Wqp, bqp, Wkvp, bkvp,
                                           q, kT, vall, qpr, kvpr);
    krot<<<dim3(768), 192, 0, stream>>>(rot, trans, qpr, kvpr, qp, kpT, vall);
    kqk<<<dim3(6, 24, 12), 256, 0, stream>>>(kT, kpT, q, qp, mask, head_w, bb, lqd);
    kbias<<<dim3(768), 256, 0, stream>>>(z, Wb, lqd, av, lsum);
    kopair<<<dim3(768), 256, 0, stream>>>(z, av, lsum, cat);
    kov<<<dim3(768), 256, 0, stream>>>(vall, av, lsum, rot, trans, cat);
    kout<<<dim3(96, 3), 256, 0, stream>>>(cat, Wout, bout, out);
}